// Round 4
// baseline (882.779 us; speedup 1.0000x reference)
//
#include <hip/hip_runtime.h>
#include <hip/hip_cooperative_groups.h>
#include <math.h>

namespace cg = cooperative_groups;

#define HH 1024
#define WW 1024
#define BB 4

// gaussian 1D weights, sigma=1, ks=5, normalized
#define GW0 0.05448868454f
#define GW1 0.24420134723f
#define GW2 0.40261994646f

// 8-neighbor table; axis uses entries 0..3 (+/- symmetric for NMS)
__constant__ int c_dy[8] = {0,1,1,1,0,-1,-1,-1};
__constant__ int c_dx[8] = {1,1,0,-1,-1,-1,0,1};

__device__ __forceinline__ int refl(int i, int n) {
    if (i < 0) i = -i;
    if (i >= n) i = 2*n - 2 - i;
    return i;
}

// One cooperative kernel: input-max (fused into gray loads) + gray + gaussian
// (reflect) + sobel (replicate) + mag/axis + NMS (zero-pad) -> sM in LDS;
// grid.sync; thresholds -> labels; grid.sync; 2 prop sweeps + final output.
// Grid: 1024 blocks = 4 batches x 16x16 supertiles (64x64 px each), 4 sub-tiles
// of 32x32 processed sequentially per block.
// LDS: sA 6560 B (gray 40x41, reused as blurV 36x37), sB 5920 B (blurH 40x37,
// reused as mag 34x35 + axis 32x32), sM 16 KB -> 28.9 KB -> 5 blk/CU by LDS;
// __launch_bounds__(256,4) caps VGPR<=128 -> 4 blk/CU -> capacity 1024 = grid.
__global__ __launch_bounds__(256, 4) void k_canny(const float* __restrict__ in,
                                                  int* __restrict__ hdr,
                                                  unsigned char* __restrict__ lab,
                                                  float* __restrict__ out) {
    __shared__ float sA[1640];            // gray (40x41=1640) / blurV (36x37=1332)
    __shared__ float sB[1480];            // blurH (40x37=1480) / mag (34x35=1190) + axis
    __shared__ float sM[4][1024];         // per-tile NMS-suppressed magnitude
    __shared__ float sred[4];
    unsigned char* sAxis = (unsigned char*)(sB + 1190);  // 1024 B, 1190*4+1024=5784 <= 5920

    const int tid = threadIdx.x;
    const int bat = blockIdx.x >> 8;                 // batch 0..3
    const int s   = blockIdx.x & 255;
    const int Y0  = (s >> 4) << 6, X0 = (s & 15) << 6;

    const float* base = in + ((size_t)(bat*3) << 20);
    unsigned char* lb = lab + ((size_t)bat << 20);

    float bmax = 0.0f;

    for (int j = 0; j < 4; ++j) {
        const int y0 = Y0 + ((j >> 1) << 5);
        const int x0 = X0 + ((j & 1) << 5);

        // stage 1: grayscale (reflect coords) + running input max
        for (int p = tid; p < 1600; p += 256) {
            int ly = p / 40, lx = p - ly*40;
            int gy = refl(y0 - 4 + ly, HH);
            int gx = refl(x0 - 4 + lx, WW);
            int o = (gy << 10) + gx;
            float r = base[o], g = base[o + (1<<20)], bc = base[o + (2<<20)];
            bmax = fmaxf(bmax, fmaxf(r, fmaxf(g, bc)));
            sA[ly*41+lx] = 0.299f*r + 0.587f*g + 0.114f*bc;
        }
        __syncthreads();
        // stage 2: horizontal gaussian (40 rows x 36 cols)
        for (int p = tid; p < 1440; p += 256) {
            int rl = p / 36, cl = p - rl*36;
            const float* gp = &sA[rl*41 + cl];
            sB[rl*37+cl] = GW0*gp[0] + GW1*gp[1] + GW2*gp[2] + GW1*gp[3] + GW0*gp[4];
        }
        __syncthreads();
        // stage 3: vertical gaussian -> sA reused (36 rows x 36 cols, pitch 37)
        for (int p = tid; p < 1296; p += 256) {
            int rl = p / 36, cl = p - rl*36;
            const float* h = &sB[rl*37 + cl];
            sA[rl*37+cl] = GW0*h[0] + GW1*h[37] + GW2*h[74] + GW1*h[111] + GW0*h[148];
        }
        __syncthreads();
        // stage 4: sobel (replicate) -> mag in sB (34x35) + axis for center 32x32
        for (int p = tid; p < 1156; p += 256) {
            int rl = p / 34, cl = p - rl*34;
            int r = y0 - 1 + rl, c = x0 - 1 + cl;
            float m = 0.0f;
            if ((unsigned)r < HH && (unsigned)c < WW) {
                int rm = (r>0)?r-1:0, rp = (r<HH-1)?r+1:HH-1;
                int cm = (c>0)?c-1:0, cp = (c<WW-1)?c+1:WW-1;
                int lrm = rm-y0+2, lr = r-y0+2, lrp = rp-y0+2;
                int lcm = cm-x0+2, lc = c-x0+2, lcp = cp-x0+2;
                float a00 = sA[lrm*37+lcm], a01 = sA[lrm*37+lc], a02 = sA[lrm*37+lcp];
                float a10 = sA[lr *37+lcm],                      a12 = sA[lr *37+lcp];
                float a20 = sA[lrp*37+lcm], a21 = sA[lrp*37+lc], a22 = sA[lrp*37+lcp];
                float gx = ((a02 - a00) + 2.0f*(a12 - a10) + (a22 - a20)) * 0.125f;
                float gy = ((a20 - a00) + 2.0f*(a21 - a01) + (a22 - a02)) * 0.125f;
                m = sqrtf(gx*gx + gy*gy + 1e-6f);
                if (rl >= 1 && rl <= 32 && cl >= 1 && cl <= 32) {
                    // octant via tan(22.5)=sqrt2-1 / tan(67.5)=sqrt2+1 boundaries;
                    // half-even rounding at boundaries -> non-diagonal side (both forms)
                    float ax = fabsf(gx), ay = fabsf(gy);
                    int axis;
                    if (ay <= 0.41421356237309503f * ax)      axis = 0;
                    else if (ay >= 2.4142135623730951f * ax)  axis = 2;
                    else axis = ((gx >= 0.0f) == (gy >= 0.0f)) ? 1 : 3;
                    sAxis[(rl-1)*32 + (cl-1)] = (unsigned char)axis;
                }
            }
            sB[rl*35+cl] = m;
        }
        __syncthreads();
        // stage 5a: directional NMS (no thresholds yet) -> sM[j]
        for (int p = tid; p < 1024; p += 256) {
            int oy = p >> 5, ox = p & 31;
            float cmag = sB[(oy+1)*35 + (ox+1)];
            int a = sAxis[(oy<<5) + ox];
            int dy = c_dy[a], dx = c_dx[a];
            float np_ = sB[(oy+1+dy)*35 + (ox+1+dx)];
            float nq  = sB[(oy+1-dy)*35 + (ox+1-dx)];
            sM[j][p] = (fminf(cmag - np_, cmag - nq) > 0.0f) ? cmag : 0.0f;
        }
        // next stage-1 writes sA (last read in stage 4, sync'ed); stage-2's
        // sync guards sB against the stage-5a reads. No extra sync needed.
    }

    // block max -> device atomic (signed-int max: poison 0xAAAAAAAA is negative,
    // inputs are nonneg floats, so int order == float order; no init needed)
    #pragma unroll
    for (int off = 32; off > 0; off >>= 1)
        bmax = fmaxf(bmax, __shfl_down(bmax, off, 64));
    if ((tid & 63) == 0) sred[tid >> 6] = bmax;
    __syncthreads();
    if (tid == 0) {
        float mm = fmaxf(fmaxf(sred[0], sred[1]), fmaxf(sred[2], sred[3]));
        atomicMax(hdr, __float_as_int(mm));
    }

    cg::this_grid().sync();

    const float mx = __int_as_float(
        __hip_atomic_load(hdr, __ATOMIC_RELAXED, __HIP_MEMORY_SCOPE_AGENT));
    const float tlo = mx * 0.1f, thi = mx * 0.4f;

    // labels: {0, 1=weak(e==0.5), 2=strong(e==1.0)}
    for (int j = 0; j < 4; ++j) {
        const int y0 = Y0 + ((j >> 1) << 5);
        const int x0 = X0 + ((j & 1) << 5);
        for (int p = tid; p < 1024; p += 256) {
            int oy = p >> 5, ox = p & 31;
            float m = sM[j][p];
            float lo = (m > tlo) ? m : 0.0f;
            float hi = (m > thi) ? m : 0.0f;
            float e = 0.5f*lo + 0.5f*hi;
            lb[((y0+oy)<<10) + (x0+ox)] =
                (e == 1.0f) ? (unsigned char)2 : (e == 0.5f) ? (unsigned char)1 : (unsigned char)0;
        }
    }
    __threadfence();
    cg::this_grid().sync();

    // 2 monotone prop sweeps over own 64x64 supertile (neighbors via global)
    const int row = tid >> 2, seg = tid & 3;
    const int y = Y0 + row, x = X0 + (seg << 4);
    unsigned char* lr0 = lb + (y << 10) + x;
    for (int sweep = 0; sweep < 2; ++sweep) {
        uint4 v = *(const uint4*)lr0;
        unsigned wd[4] = {v.x, v.y, v.z, v.w};
        bool any = false;
        #pragma unroll
        for (int q = 0; q < 4; ++q) {
            unsigned z = wd[q] ^ 0x01010101u;               // SWAR: any byte == 1?
            if (((z - 0x01010101u) & ~z & 0x80808080u) != 0u) any = true;
        }
        if (any) {
            for (int k = 0; k < 16; ++k) {
                if (lr0[k] != 1) continue;
                int xc = x + k;
                bool st = false;
                #pragma unroll
                for (int n = 0; n < 8; ++n) {
                    int yy = y + c_dy[n], xx = xc + c_dx[n];
                    if ((unsigned)yy < HH && (unsigned)xx < WW && lb[(yy<<10)+xx] == 2) st = true;
                }
                if (st) lr0[k] = 2;
            }
        }
        __threadfence();
        cg::this_grid().sync();
    }

    // final: strong -> 1.0; weak with strong neighbor -> 1.0; else 0
    {
        uint4 v = *(const uint4*)lr0;
        unsigned wd[4] = {v.x, v.y, v.z, v.w};
        float res[16];
        #pragma unroll
        for (int q = 0; q < 4; ++q) {
            #pragma unroll
            for (int k = 0; k < 4; ++k) {
                unsigned byt = (wd[q] >> (8*k)) & 0xffu;
                float val = 0.0f;
                if (byt == 2u) val = 1.0f;
                else if (byt == 1u) {
                    int xc = x + (q << 2) + k;
                    #pragma unroll
                    for (int n = 0; n < 8; ++n) {
                        int yy = y + c_dy[n], xx = xc + c_dx[n];
                        if ((unsigned)yy < HH && (unsigned)xx < WW && lb[(yy<<10)+xx] == 2) val = 1.0f;
                    }
                }
                res[(q << 2) + k] = val;
            }
        }
        float4* o4 = (float4*)(out + ((size_t)bat << 20) + (y << 10) + x);
        o4[0] = make_float4(res[0],  res[1],  res[2],  res[3]);
        o4[1] = make_float4(res[4],  res[5],  res[6],  res[7]);
        o4[2] = make_float4(res[8],  res[9],  res[10], res[11]);
        o4[3] = make_float4(res[12], res[13], res[14], res[15]);
    }
}

extern "C" void kernel_launch(void* const* d_in, const int* in_sizes, int n_in,
                              void* d_out, int out_size, void* d_ws, size_t ws_size,
                              hipStream_t stream) {
    const float* in = (const float*)d_in[0];
    float* out = (float*)d_out;
    int* hdr = (int*)d_ws;
    unsigned char* lab = (unsigned char*)((char*)d_ws + 256);

    void* args[] = { (void*)&in, (void*)&hdr, (void*)&lab, (void*)&out };
    hipLaunchCooperativeKernel(reinterpret_cast<void*>(k_canny),
                               dim3(1024), dim3(256), args, 0, stream);
}

// Round 5
// 156.856 us; speedup vs baseline: 5.6280x; 5.6280x over previous
//
#include <hip/hip_runtime.h>
#include <math.h>

#define HH 1024
#define WW 1024
#define BB 4

// gaussian 1D weights, sigma=1, ks=5, normalized
#define GW0 0.05448868454f
#define GW1 0.24420134723f
#define GW2 0.40261994646f

// 8-neighbor table; NMS uses +/- of entries 0..3 (min(cp,cn) symmetric)
__constant__ int c_dy[8] = {0,1,1,1,0,-1,-1,-1};
__constant__ int c_dx[8] = {1,1,0,-1,-1,-1,0,1};

__device__ __forceinline__ int refl(int i, int n) {
    if (i < 0) i = -i;
    if (i >= n) i = 2*n - 2 - i;
    return i;
}

// Fused: gray + input-max + gaussian(reflect) + sobel(replicate) + mag/axis +
// NMS(zero-pad) -> suppressed magnitude plane (fp32) + global max via atomicMax.
// Tile 32x32 outputs per block; halo 4 (blur 2+2, sobel 1, nms 1). LDS ~12.5 KB.
__global__ __launch_bounds__(256) void k_fused(const float* __restrict__ in,
                                               int* __restrict__ hdr,
                                               float* __restrict__ mag) {
    __shared__ float sA[1640];            // gray (40x41) / blurV (36x37)
    __shared__ float sB[1480];            // blurH (40x37) / mag (34x35=1190) + axis
    __shared__ float sred[4];
    unsigned char* sAxis = (unsigned char*)(sB + 1190);  // 1024 B, fits (1446<=1480)

    const int tid = threadIdx.x;
    const int b = blockIdx.x >> 10;
    const int t = blockIdx.x & 1023;
    const int y0 = (t >> 5) << 5, x0 = (t & 31) << 5;
    const float* base = in + ((size_t)(b*3) << 20);

    float bmax = 0.0f;

    // stage 1: grayscale (reflect coords, always in-bounds) + running input max
    for (int p = tid; p < 1600; p += 256) {
        int ly = p / 40, lx = p - ly*40;
        int gy = refl(y0 - 4 + ly, HH);
        int gx = refl(x0 - 4 + lx, WW);
        int o = (gy << 10) + gx;
        float r = base[o], g = base[o + (1<<20)], bc = base[o + (2<<20)];
        bmax = fmaxf(bmax, fmaxf(r, fmaxf(g, bc)));
        sA[ly*41+lx] = 0.299f*r + 0.587f*g + 0.114f*bc;
    }
    __syncthreads();
    // stage 2: horizontal gaussian (40 rows x 36 cols)
    for (int p = tid; p < 1440; p += 256) {
        int rl = p / 36, cl = p - rl*36;
        const float* gp = &sA[rl*41 + cl];
        sB[rl*37+cl] = GW0*gp[0] + GW1*gp[1] + GW2*gp[2] + GW1*gp[3] + GW0*gp[4];
    }
    __syncthreads();
    // stage 3: vertical gaussian -> sA reused (36x36, pitch 37)
    for (int p = tid; p < 1296; p += 256) {
        int rl = p / 36, cl = p - rl*36;
        const float* h = &sB[rl*37 + cl];
        sA[rl*37+cl] = GW0*h[0] + GW1*h[37] + GW2*h[74] + GW1*h[111] + GW0*h[148];
    }
    __syncthreads();
    // stage 4: sobel (replicate) -> mag into sB (34x35) + axis for center 32x32
    for (int p = tid; p < 1156; p += 256) {
        int rl = p / 34, cl = p - rl*34;
        int r = y0 - 1 + rl, c = x0 - 1 + cl;
        float m = 0.0f;
        if ((unsigned)r < HH && (unsigned)c < WW) {
            int rm = (r>0)?r-1:0, rp = (r<HH-1)?r+1:HH-1;
            int cm = (c>0)?c-1:0, cp = (c<WW-1)?c+1:WW-1;
            int lrm = rm-y0+2, lr = r-y0+2, lrp = rp-y0+2;
            int lcm = cm-x0+2, lc = c-x0+2, lcp = cp-x0+2;
            float a00 = sA[lrm*37+lcm], a01 = sA[lrm*37+lc], a02 = sA[lrm*37+lcp];
            float a10 = sA[lr *37+lcm],                      a12 = sA[lr *37+lcp];
            float a20 = sA[lrp*37+lcm], a21 = sA[lrp*37+lc], a22 = sA[lrp*37+lcp];
            float gx = ((a02 - a00) + 2.0f*(a12 - a10) + (a22 - a20)) * 0.125f;
            float gy = ((a20 - a00) + 2.0f*(a21 - a01) + (a22 - a02)) * 0.125f;
            m = sqrtf(gx*gx + gy*gy + 1e-6f);
            if (rl >= 1 && rl <= 32 && cl >= 1 && cl <= 32) {
                // octant via tan(22.5)=sqrt2-1 / tan(67.5)=sqrt2+1; half-even
                // rounding at exact boundaries lands non-diagonal in both forms
                float ax = fabsf(gx), ay = fabsf(gy);
                int axis;
                if (ay <= 0.41421356237309503f * ax)      axis = 0;
                else if (ay >= 2.4142135623730951f * ax)  axis = 2;
                else axis = ((gx >= 0.0f) == (gy >= 0.0f)) ? 1 : 3;
                sAxis[(rl-1)*32 + (cl-1)] = (unsigned char)axis;
            }
        }
        sB[rl*35+cl] = m;
    }
    __syncthreads();
    // stage 5: directional NMS -> suppressed magnitude to global
    float* mrow = mag + ((size_t)b << 20);
    for (int p = tid; p < 1024; p += 256) {
        int oy = p >> 5, ox = p & 31;
        float cmag = sB[(oy+1)*35 + (ox+1)];
        int a = sAxis[(oy<<5) + ox];
        int dy = c_dy[a], dx = c_dx[a];
        float np_ = sB[(oy+1+dy)*35 + (ox+1+dx)];
        float nq  = sB[(oy+1-dy)*35 + (ox+1-dx)];
        mrow[((y0+oy)<<10) + (x0+ox)] =
            (fminf(cmag - np_, cmag - nq) > 0.0f) ? cmag : 0.0f;
    }

    // block input-max -> device atomicMax (signed-int trick: ws poison
    // 0xAAAAAAAA is negative as int; inputs nonneg -> int order == float order)
    #pragma unroll
    for (int off = 32; off > 0; off >>= 1)
        bmax = fmaxf(bmax, __shfl_down(bmax, off, 64));
    if ((tid & 63) == 0) sred[tid >> 6] = bmax;
    __syncthreads();
    if (tid == 0) {
        float mm = fmaxf(fmaxf(sred[0], sred[1]), fmaxf(sred[2], sred[3]));
        atomicMax(hdr, __float_as_int(mm));
    }
}

// Labels (pointwise from m + thresholds) + 3 in-place monotone promotion
// sweeps in LDS + final output. Tile 64x64 per block, halo 3 -> center gets
// >= simultaneous-update depth-3 promotion (all promotions bounded by the
// true reachability closure; never demotes).
__global__ __launch_bounds__(256) void k_edges(const float* __restrict__ mag,
                                               const int* __restrict__ hdr,
                                               float* __restrict__ out) {
    __shared__ unsigned char sL[70*72];   // 70 rows x 70 cols used, pitch 72

    const int tid = threadIdx.x;
    const int bat = blockIdx.x >> 8;
    const int s = blockIdx.x & 255;
    const int Y0 = (s >> 4) << 6, X0 = (s & 15) << 6;
    const float* mrow = mag + ((size_t)bat << 20);

    const float mx = __int_as_float(hdr[0]);
    const float tlo = mx * 0.1f, thi = mx * 0.4f;

    // zero-init (covers pad cols + out-of-image halo)
    for (int w = tid; w < 70*72/4; w += 256) ((unsigned*)sL)[w] = 0u;
    __syncthreads();

    // labels for the 70x70 region: {0, 1=weak(e==0.5), 2=strong(e==1.0)}
    for (int p = tid; p < 4900; p += 256) {
        int ly = p / 70, lx = p - ly*70;
        int gy = Y0 - 3 + ly, gx = X0 - 3 + lx;
        if ((unsigned)gy < HH && (unsigned)gx < WW) {
            float m = mrow[(gy << 10) + gx];
            float lo = (m > tlo) ? m : 0.0f;
            float hi = (m > thi) ? m : 0.0f;
            float e = 0.5f*lo + 0.5f*hi;
            sL[ly*72+lx] = (e == 1.0f) ? (unsigned char)2
                         : (e == 0.5f) ? (unsigned char)1 : (unsigned char)0;
        }
    }
    __syncthreads();

    // 3 in-place promotion sweeps (SWAR fast-skip on words with no weak byte)
    for (int sweep = 0; sweep < 3; ++sweep) {
        for (int w = tid; w < 70*72/4; w += 256) {
            unsigned word = ((unsigned*)sL)[w];
            unsigned z = word ^ 0x01010101u;            // any byte == 1?
            if (((z - 0x01010101u) & ~z & 0x80808080u) == 0u) continue;
            int p0 = w << 2;
            #pragma unroll
            for (int k = 0; k < 4; ++k) {
                if (((word >> (8*k)) & 0xffu) != 1u) continue;
                int p = p0 + k;
                int ly = p / 72, lx = p - ly*72;
                if (lx >= 70) continue;                 // pad
                bool st = false;
                #pragma unroll
                for (int n = 0; n < 8; ++n) {
                    int yy = ly + c_dy[n], xx = lx + c_dx[n];
                    if ((unsigned)yy < 70 && (unsigned)xx < 70 && sL[yy*72+xx] == 2)
                        st = true;
                }
                if (st) sL[ly*72+lx] = 2;
            }
        }
        __syncthreads();
    }

    // final: strong -> 1.0; weak with strong neighbor -> 1.0; else 0
    float* orow = out + ((size_t)bat << 20);
    for (int p = tid; p < 4096; p += 256) {
        int oy = p >> 6, ox = p & 63;
        int ly = oy + 3, lx = ox + 3;
        unsigned char l = sL[ly*72+lx];
        float v = 0.0f;
        if (l == 2) v = 1.0f;
        else if (l == 1) {
            #pragma unroll
            for (int n = 0; n < 8; ++n) {
                if (sL[(ly+c_dy[n])*72 + (lx+c_dx[n])] == 2) v = 1.0f;
            }
        }
        orow[((Y0+oy)<<10) + (X0+ox)] = v;
    }
}

extern "C" void kernel_launch(void* const* d_in, const int* in_sizes, int n_in,
                              void* d_out, int out_size, void* d_ws, size_t ws_size,
                              hipStream_t stream) {
    const float* in = (const float*)d_in[0];
    float* out = (float*)d_out;
    int* hdr = (int*)d_ws;
    float* mag = (float*)((char*)d_ws + 256);

    k_fused<<<BB*32*32, 256, 0, stream>>>(in, hdr, mag);
    k_edges<<<BB*16*16, 256, 0, stream>>>(mag, hdr, out);
}

// Round 6
// 118.517 us; speedup vs baseline: 7.4486x; 1.3235x over previous
//
#include <hip/hip_runtime.h>
#include <math.h>

#define HH 1024
#define WW 1024
#define BB 4

// gaussian 1D weights, sigma=1, ks=5, normalized
#define GW0 0.05448868454f
#define GW1 0.24420134723f
#define GW2 0.40261994646f

// 8-neighbor table; NMS uses +/- of entries 0..3 (min(cp,cn) symmetric)
__constant__ int c_dy[8] = {0,1,1,1,0,-1,-1,-1};
__constant__ int c_dx[8] = {1,1,0,-1,-1,-1,0,1};

__device__ __forceinline__ int refl(int i, int n) {
    if (i < 0) i = -i;
    if (i >= n) i = 2*n - 2 - i;
    return i;
}

// Fused: gray + input-max + gaussian(reflect) + sobel(replicate) + mag/axis +
// NMS(zero-pad) -> suppressed magnitude plane (fp32) + max into 64 spread slots.
// Tile 32x32 outputs per block; halo 4. LDS ~13 KB.
__global__ __launch_bounds__(256) void k_fused(const float* __restrict__ in,
                                               int* __restrict__ hdr,
                                               float* __restrict__ mag) {
    __shared__ float sA[1760];            // gray 40x44 (pitch 44, 16B-aligned rows) / blurV 36x37
    __shared__ float sB[1480];            // blurH 40x37 / mag 34x35 (=1190) + axis
    __shared__ float sred[4];
    unsigned char* sAxis = (unsigned char*)(sB + 1190);  // 1024 B (5784 <= 5920)

    const int tid = threadIdx.x;
    const int b = blockIdx.x >> 10;
    const int t = blockIdx.x & 1023;
    const int y0 = (t >> 5) << 5, x0 = (t & 31) << 5;
    const float* base = in + ((size_t)(b*3) << 20);

    float bmax = 0.0f;

    // stage 1: grayscale + running input max.
    // Fast path (x-interior tiles, 30/32): aligned float4 row-segment loads.
    if (x0 != 0 && x0 != WW-32) {
        for (int u = tid; u < 400; u += 256) {       // 40 rows x 10 float4-segs
            int ly = u / 10, seg = u - ly*10;
            int gy = refl(y0 - 4 + ly, HH);
            const float* rp = base + (gy << 10) + (x0 - 4);
            float4 R = ((const float4*)rp)[seg];
            float4 G = ((const float4*)(rp + (1<<20)))[seg];
            float4 Bv = ((const float4*)(rp + (2<<20)))[seg];
            bmax = fmaxf(bmax, fmaxf(fmaxf(fmaxf(R.x,R.y),fmaxf(R.z,R.w)),
                          fmaxf(fmaxf(fmaxf(G.x,G.y),fmaxf(G.z,G.w)),
                                fmaxf(fmaxf(Bv.x,Bv.y),fmaxf(Bv.z,Bv.w)))));
            ((float4*)(sA + ly*44))[seg] = make_float4(
                0.299f*R.x + 0.587f*G.x + 0.114f*Bv.x,
                0.299f*R.y + 0.587f*G.y + 0.114f*Bv.y,
                0.299f*R.z + 0.587f*G.z + 0.114f*Bv.z,
                0.299f*R.w + 0.587f*G.w + 0.114f*Bv.w);
        }
    } else {
        for (int p = tid; p < 1600; p += 256) {
            int ly = p / 40, lx = p - ly*40;
            int gy = refl(y0 - 4 + ly, HH);
            int gx = refl(x0 - 4 + lx, WW);
            int o = (gy << 10) + gx;
            float r = base[o], g = base[o + (1<<20)], bc = base[o + (2<<20)];
            bmax = fmaxf(bmax, fmaxf(r, fmaxf(g, bc)));
            sA[ly*44+lx] = 0.299f*r + 0.587f*g + 0.114f*bc;
        }
    }
    __syncthreads();
    // stage 2: horizontal gaussian (40 rows x 36 cols)
    for (int p = tid; p < 1440; p += 256) {
        int rl = p / 36, cl = p - rl*36;
        const float* gp = &sA[rl*44 + cl];
        sB[rl*37+cl] = GW0*gp[0] + GW1*gp[1] + GW2*gp[2] + GW1*gp[3] + GW0*gp[4];
    }
    __syncthreads();
    // stage 3: vertical gaussian -> sA reused (36x36, pitch 37)
    for (int p = tid; p < 1296; p += 256) {
        int rl = p / 36, cl = p - rl*36;
        const float* h = &sB[rl*37 + cl];
        sA[rl*37+cl] = GW0*h[0] + GW1*h[37] + GW2*h[74] + GW1*h[111] + GW0*h[148];
    }
    __syncthreads();
    // stage 4: sobel (replicate) -> mag into sB (34x35) + axis for center 32x32
    for (int p = tid; p < 1156; p += 256) {
        int rl = p / 34, cl = p - rl*34;
        int r = y0 - 1 + rl, c = x0 - 1 + cl;
        float m = 0.0f;
        if ((unsigned)r < HH && (unsigned)c < WW) {
            int rm = (r>0)?r-1:0, rp = (r<HH-1)?r+1:HH-1;
            int cm = (c>0)?c-1:0, cp = (c<WW-1)?c+1:WW-1;
            int lrm = rm-y0+2, lr = r-y0+2, lrp = rp-y0+2;
            int lcm = cm-x0+2, lc = c-x0+2, lcp = cp-x0+2;
            float a00 = sA[lrm*37+lcm], a01 = sA[lrm*37+lc], a02 = sA[lrm*37+lcp];
            float a10 = sA[lr *37+lcm],                      a12 = sA[lr *37+lcp];
            float a20 = sA[lrp*37+lcm], a21 = sA[lrp*37+lc], a22 = sA[lrp*37+lcp];
            float gx = ((a02 - a00) + 2.0f*(a12 - a10) + (a22 - a20)) * 0.125f;
            float gy = ((a20 - a00) + 2.0f*(a21 - a01) + (a22 - a02)) * 0.125f;
            m = sqrtf(gx*gx + gy*gy + 1e-6f);
            if (rl >= 1 && rl <= 32 && cl >= 1 && cl <= 32) {
                // octant via tan(22.5)=sqrt2-1 / tan(67.5)=sqrt2+1; half-even
                // rounding at exact boundaries lands non-diagonal in both forms
                float ax = fabsf(gx), ay = fabsf(gy);
                int axis;
                if (ay <= 0.41421356237309503f * ax)      axis = 0;
                else if (ay >= 2.4142135623730951f * ax)  axis = 2;
                else axis = ((gx >= 0.0f) == (gy >= 0.0f)) ? 1 : 3;
                sAxis[(rl-1)*32 + (cl-1)] = (unsigned char)axis;
            }
        }
        sB[rl*35+cl] = m;
    }
    __syncthreads();
    // stage 5: directional NMS -> suppressed magnitude, float4 stores
    float* mrow = mag + ((size_t)b << 20);
    for (int p = tid; p < 256; p += 256) {
        int oy = p >> 3, ox0 = (p & 7) << 2;
        float r4[4];
        #pragma unroll
        for (int k = 0; k < 4; ++k) {
            int ox = ox0 + k;
            float cmag = sB[(oy+1)*35 + (ox+1)];
            int a = sAxis[(oy<<5) + ox];
            int dy = c_dy[a], dx = c_dx[a];
            float np_ = sB[(oy+1+dy)*35 + (ox+1+dx)];
            float nq  = sB[(oy+1-dy)*35 + (ox+1-dx)];
            r4[k] = (fminf(cmag - np_, cmag - nq) > 0.0f) ? cmag : 0.0f;
        }
        *(float4*)(mrow + ((y0+oy)<<10) + x0 + ox0) = make_float4(r4[0],r4[1],r4[2],r4[3]);
    }

    // block max -> one of 64 spread slots (128 B apart) to avoid same-line
    // atomic ping-pong. Signed-int max trick: poison 0xAAAAAAAA is negative,
    // inputs nonneg -> int order == float order; no init kernel needed.
    #pragma unroll
    for (int off = 32; off > 0; off >>= 1)
        bmax = fmaxf(bmax, __shfl_down(bmax, off, 64));
    if ((tid & 63) == 0) sred[tid >> 6] = bmax;
    __syncthreads();
    if (tid == 0) {
        float mm = fmaxf(fmaxf(sred[0], sred[1]), fmaxf(sred[2], sred[3]));
        atomicMax(&hdr[(blockIdx.x & 63) << 5], __float_as_int(mm));
    }
}

// Labels (from mag + thresholds) + 3 in-place monotone promotion sweeps in LDS
// + final output. Tile 64x64 per block, window 70 rows x 72 cols (halo 3/4).
__global__ __launch_bounds__(256) void k_edges(const float* __restrict__ mag,
                                               const int* __restrict__ hdr,
                                               float* __restrict__ out) {
    __shared__ unsigned char sL[70*72];   // rows Y0-3..Y0+66, cols X0-4..X0+67
    __shared__ float sMax;

    const int tid = threadIdx.x;
    const int bat = blockIdx.x >> 8;
    const int s = blockIdx.x & 255;
    const int Y0 = (s >> 4) << 6, X0 = (s & 15) << 6;
    const float* mrow = mag + ((size_t)bat << 20);

    // reduce the 64 max slots (all were written: 4096 blocks / 64 slots)
    if (tid < 64) {
        int v = hdr[tid << 5];
        #pragma unroll
        for (int off = 32; off > 0; off >>= 1)
            v = max(v, __shfl_down(v, off, 64));
        if (tid == 0) sMax = __int_as_float(v);
    }
    __syncthreads();
    const float mx = sMax;
    const float tlo = mx * 0.1f, thi = mx * 0.4f;

    // labels for the 70x72 window, 4 px per u32 (edge quads are entirely
    // out-of-image since X0 is a multiple of 64 -> clean zero fill)
    for (int u = tid; u < 70*18; u += 256) {
        int ly = u / 18, seg = u - ly*18;
        int gy = Y0 - 3 + ly;
        int gx0 = X0 - 4 + (seg << 2);
        unsigned w = 0u;
        if ((unsigned)gy < HH && gx0 >= 0 && gx0 + 3 < WW) {
            float4 v = *(const float4*)(mrow + (gy << 10) + gx0);
            float mv[4] = {v.x, v.y, v.z, v.w};
            #pragma unroll
            for (int k = 0; k < 4; ++k) {
                float m = mv[k];
                float lo = (m > tlo) ? m : 0.0f;
                float hi = (m > thi) ? m : 0.0f;
                float e = 0.5f*lo + 0.5f*hi;
                unsigned lb = (e == 1.0f) ? 2u : (e == 0.5f) ? 1u : 0u;
                w |= lb << (8*k);
            }
        }
        ((unsigned*)sL)[ly*18 + seg] = w;
    }
    __syncthreads();

    // 3 in-place promotion sweeps (SWAR fast-skip on words with no weak byte)
    for (int sweep = 0; sweep < 3; ++sweep) {
        for (int w = tid; w < 70*18; w += 256) {
            unsigned word = ((unsigned*)sL)[w];
            unsigned z = word ^ 0x01010101u;            // any byte == 1?
            if (((z - 0x01010101u) & ~z & 0x80808080u) == 0u) continue;
            int ly = w / 18, lx0 = (w - ly*18) << 2;
            #pragma unroll
            for (int k = 0; k < 4; ++k) {
                if (((word >> (8*k)) & 0xffu) != 1u) continue;
                int lx = lx0 + k;
                bool st = false;
                #pragma unroll
                for (int n = 0; n < 8; ++n) {
                    int yy = ly + c_dy[n], xx = lx + c_dx[n];
                    if ((unsigned)yy < 70 && (unsigned)xx < 72 && sL[yy*72+xx] == 2)
                        st = true;
                }
                if (st) sL[ly*72+lx] = 2;
            }
        }
        __syncthreads();
    }

    // final: strong -> 1.0; weak with strong neighbor -> 1.0; else 0 (float4 out)
    float* orow = out + ((size_t)bat << 20);
    for (int u = tid; u < 1024; u += 256) {
        int oy = u >> 4, ox0 = (u & 15) << 2;
        int ly = oy + 3;
        float r4[4];
        #pragma unroll
        for (int k = 0; k < 4; ++k) {
            int lx = ox0 + k + 4;
            unsigned char l = sL[ly*72+lx];
            float v = 0.0f;
            if (l == 2) v = 1.0f;
            else if (l == 1) {
                #pragma unroll
                for (int n = 0; n < 8; ++n) {
                    if (sL[(ly+c_dy[n])*72 + (lx+c_dx[n])] == 2) v = 1.0f;
                }
            }
            r4[k] = v;
        }
        *(float4*)(orow + ((Y0+oy)<<10) + X0 + ox0) = make_float4(r4[0],r4[1],r4[2],r4[3]);
    }
}

extern "C" void kernel_launch(void* const* d_in, const int* in_sizes, int n_in,
                              void* d_out, int out_size, void* d_ws, size_t ws_size,
                              hipStream_t stream) {
    const float* in = (const float*)d_in[0];
    float* out = (float*)d_out;
    int* hdr = (int*)d_ws;                           // 64 slots x 128 B = 8 KB
    float* mag = (float*)((char*)d_ws + 32768);

    k_fused<<<BB*32*32, 256, 0, stream>>>(in, hdr, mag);
    k_edges<<<BB*16*16, 256, 0, stream>>>(mag, hdr, out);
}